// Round 22
// baseline (607.942 us; speedup 1.0000x reference)
//
#include <hip/hip_runtime.h>
#include <hip/hip_fp16.h>

// ---------------------------------------------------------------------------
// MLPForwardPolicy — r20 champion + A off the DMA queue (reg-staged via L2).
//
// Accounting: r20's A-DMA totals 1.28 GB = W itself; the global_load_lds
// queue flattens all sources to ~6 TB/s (r19/r20 evidence). Fix: W stays on
// counted gload_lds (HBM-paced); A rides global_load->VGPR->ds_write with a
// ~3200cy lead vs ~400cy L2 latency, so compiler-inserted waits (r8/r17
// failure mode) resolve instantly. Ledger: queue at loop top =
// [W(t),W(t+1),Areg(t+1)] -> vmcnt(8) steady / 0 tail; lgkmcnt(0) at top
// flushes A ds_writes. Body order: issueW(t+2), writeA(t+1), loadAreg(t+2).
// Ranking: r20=499 r19=514 r21=535 r16/r18=561 r11=592 r7=606.
// ---------------------------------------------------------------------------

typedef _Float16 f16;
typedef _Float16 f16x4 __attribute__((ext_vector_type(4)));
typedef _Float16 f16x8 __attribute__((ext_vector_type(8)));
typedef float f32x4 __attribute__((ext_vector_type(4)));

#define DH 9216
#define SPLIT 8960

__device__ __forceinline__ void gload16(const void* g, void* l) {
    __builtin_amdgcn_global_load_lds(
        (const __attribute__((address_space(1))) void*)g,
        (__attribute__((address_space(3))) void*)l, 16, 0, 0);
}

// packed-granule byte offset for element (row, k)
__device__ __forceinline__ size_t pk_off(int row, int k) {
    int tk = k >> 5, q = (k >> 3) & 3;
    int mhalf = row >> 7, wmA = (row >> 6) & 1, ri = (row >> 4) & 3, lc = row & 15;
    int h = (wmA << 8) | (ri << 6) | (q << 4) | lc;
    return (size_t)(tk * 2 + mhalf) * 8192 + (size_t)h * 16;
}

// ---------------- f32 -> packed f16 granules (for A0) ----------------
__global__ void cvt_kernel(const float* __restrict__ in, char* __restrict__ outp) {
    int idx = blockIdx.x * blockDim.x + threadIdx.x;   // [0, 524288)
    int row = idx >> 11;
    int k8  = (idx & 2047) << 3;
    const float* src = in + ((size_t)row << 14) + k8;
    f16x8 h;
#pragma unroll
    for (int j = 0; j < 8; ++j) h[j] = (_Float16)src[j];
    *(f16x8*)(outp + pk_off(row, k8)) = h;
}

// ---------------- streaming GEMM: P[y] = A[256,Kh] @ W[Kh, 128-col] ---------
// linear grid 72<<yshift blocks of 256 threads; y = bid & (S-1)
// n0 = (bid >> yshift) * 128
// 4 waves 2x2: wave(wm,wn) owns rows wm*128..+128 x cols n0+wn*64..+64
__global__ __launch_bounds__(256, 2) void gemm_kernel(
    const char* __restrict__ Ap, int K, int Kh, int yshift,
    const float* __restrict__ W,
    f16* __restrict__ P)   // [S][256][9216] f16 partials
{
    __shared__ __align__(16) char lds[2][32768];   // [W 16K][A 16K] x2
    const int bid  = blockIdx.x;
    const int y    = bid & ((1 << yshift) - 1);
    const int n0   = (bid >> yshift) << 7;
    const int tid  = threadIdx.x;
    const int lane = tid & 63;
    const int wid  = tid >> 6;
    const int wm   = wid >> 1, wn = wid & 1;
    const int kbase = y * Kh;
    const int ns   = Kh >> 5;                     // BK = 32 (64 or 36)

    f32x4 acc[8][4] = {};
    f16x8 ar0, ar1, ar2, ar3;                     // A reg-stage (one stage)

    // ---- hoisted W DMA source pointers ----
    const float* wsrc0;
    const float* wsrc1;
    const float* wsrc2;
    const float* wsrc3;
    {
        int g0 = tid,      k0 = g0 >> 5, c0 = (g0 & 31) ^ ((5 * (k0 >> 3)) & 31);
        int g1 = tid + 256, k1 = g1 >> 5, c1 = (g1 & 31) ^ ((5 * (k1 >> 3)) & 31);
        int g2 = tid + 512, k2 = g2 >> 5, c2 = (g2 & 31) ^ ((5 * (k2 >> 3)) & 31);
        int g3 = tid + 768, k3 = g3 >> 5, c3 = (g3 & 31) ^ ((5 * (k3 >> 3)) & 31);
        wsrc0 = W + (size_t)(kbase + k0) * DH + n0 + (c0 << 2);
        wsrc1 = W + (size_t)(kbase + k1) * DH + n0 + (c1 << 2);
        wsrc2 = W + (size_t)(kbase + k2) * DH + n0 + (c2 << 2);
        wsrc3 = W + (size_t)(kbase + k3) * DH + n0 + (c3 << 2);
    }
    // packed A: per-thread pointer; stage t at apt + t*16384
    const char* apt = Ap + (size_t)(y * (Kh >> 5) * 2) * 8192 + (size_t)tid * 16;

    auto issueW = [&](int slot) {     // 4 DMA instr/thread; advance 1 stage
        char* dst = &lds[slot][0];
        gload16(wsrc0, dst + (size_t)tid * 16);          wsrc0 += 32 * DH;
        gload16(wsrc1, dst + (size_t)(tid + 256) * 16);  wsrc1 += 32 * DH;
        gload16(wsrc2, dst + (size_t)(tid + 512) * 16);  wsrc2 += 32 * DH;
        gload16(wsrc3, dst + (size_t)(tid + 768) * 16);  wsrc3 += 32 * DH;
    };
    auto loadAreg = [&]() {           // 4 x global_load_dwordx4; advance 1 stage
        ar0 = *(const f16x8*)(apt);
        ar1 = *(const f16x8*)(apt + 4096);
        ar2 = *(const f16x8*)(apt + 8192);
        ar3 = *(const f16x8*)(apt + 12288);
        apt += 16384;
    };
    auto writeA = [&](int slot) {     // 4 x ds_write_b128 (disjoint per tid)
        char* dst = &lds[slot][16384] + (size_t)tid * 16;
        *(f16x8*)(dst)         = ar0;
        *(f16x8*)(dst + 4096)  = ar1;
        *(f16x8*)(dst + 8192)  = ar2;
        *(f16x8*)(dst + 12288) = ar3;
    };

    const int q  = lane >> 4;
    const int lc = lane & 15;
    auto step = [&](int slot) {
        const float* wl = (const float*)&lds[slot][0];
        const f16*   al = (const f16*)&lds[slot][16384];
        f16x8 af[8], bf[4];
#pragma unroll
        for (int ri8 = 0; ri8 < 8; ++ri8) {
            int off = (wm << 12) + (((ri8 >> 2) << 8) | ((ri8 & 3) << 6)) + lane;
            af[ri8] = *(const f16x8*)(al + ((size_t)off << 3));
        }
        const int wbase = (q << 10) + (lc & 3);
#pragma unroll
        for (int ni = 0; ni < 4; ++ni) {
            int p = ((wn << 4) + (ni << 2) + (lc >> 2)) ^ (5 * q);
            int fi = wbase + ((p & 31) << 2);
            f16x8 b;
#pragma unroll
            for (int j = 0; j < 8; ++j)
                b[j] = (_Float16)wl[fi + (j << 7)];
            bf[ni] = b;
        }
#pragma unroll
        for (int ri = 0; ri < 8; ++ri)
#pragma unroll
            for (int ni = 0; ni < 4; ++ni)
                acc[ri][ni] = __builtin_amdgcn_mfma_f32_16x16x32_f16(
                    af[ri], bf[ni], acc[ri][ni], 0, 0, 0);
    };

    // prologue: A(0),A(1) staged via regs; W(0),W(1) DMA'd; A(2) regs loaded.
    loadAreg(); writeA(0);            // compiler waits A(0) regs (one-time)
    loadAreg(); writeA(1);
    issueW(0);
    issueW(1);
    loadAreg();                       // A(2) regs, written at end of iter 0
    __builtin_amdgcn_sched_barrier(0);

    for (int t = 0; t < ns; ++t) {
        if (t + 1 < ns) asm volatile("s_waitcnt vmcnt(8)" ::: "memory");
        else            asm volatile("s_waitcnt vmcnt(0)" ::: "memory");
        asm volatile("s_waitcnt lgkmcnt(0)" ::: "memory");   // flush writeA
        __builtin_amdgcn_sched_barrier(0);
        __builtin_amdgcn_s_barrier();
        __builtin_amdgcn_sched_barrier(0);
        step(t & 1);
        __builtin_amdgcn_sched_barrier(0);
        asm volatile("s_waitcnt lgkmcnt(0)" ::: "memory");
        __builtin_amdgcn_sched_barrier(0);
        __builtin_amdgcn_s_barrier();
        __builtin_amdgcn_sched_barrier(0);
        if (t + 2 < ns) issueW(t & 1);          // W(t+2) -> just-freed slot
        if (t + 1 < ns) writeA((t + 1) & 1);    // A(t+1) (regs: 1-step lead)
        if (t + 2 < ns) loadAreg();             // A(t+2) regs
        __builtin_amdgcn_sched_barrier(0);
    }

    // epilogue: D layout col=lane&15, row=(lane>>4)*4+reg  [m89-verified]
    f16* Pb = P + (size_t)y * (256 * DH);
#pragma unroll
    for (int ri = 0; ri < 8; ++ri) {
        int row = wm * 128 + ri * 16 + (q << 2);
#pragma unroll
        for (int ni = 0; ni < 4; ++ni) {
            int col = n0 + wn * 64 + ni * 16 + lc;
#pragma unroll
            for (int rg = 0; rg < 4; ++rg)
                Pb[(size_t)(row + rg) * DH + col] = (_Float16)acc[ri][ni][rg];
        }
    }
}

// ---------------- splitK reduce (f16 partials) + bias + relu ----------------
// ohp != null: write PACKED granules (pk_off layout)
__global__ __launch_bounds__(256) void reduce_kernel(
    const f16* __restrict__ P, int S,
    const float* __restrict__ bias,
    char* __restrict__ ohp, float* __restrict__ out32) {
    const size_t n = 256 * DH;
    const size_t i = ((size_t)blockIdx.x * 256 + threadIdx.x) * 8;
    if (i >= n) return;
    const int row = (int)(i / DH);
    const int d   = (int)(i % DH);
    float r[8];
    {
        float4 b0 = *(const float4*)(bias + d);
        float4 b1 = *(const float4*)(bias + d + 4);
        r[0] = b0.x; r[1] = b0.y; r[2] = b0.z; r[3] = b0.w;
        r[4] = b1.x; r[5] = b1.y; r[6] = b1.z; r[7] = b1.w;
    }
    for (int j = 0; j < S; ++j) {
        f16x8 v = *(const f16x8*)(P + (size_t)j * n + i);
#pragma unroll
        for (int e = 0; e < 8; ++e) r[e] += (float)v[e];
    }
#pragma unroll
    for (int e = 0; e < 8; ++e) r[e] = fmaxf(r[e], 0.f);
    if (ohp) {
        f16x8 h;
#pragma unroll
        for (int e = 0; e < 8; ++e) h[e] = (_Float16)r[e];
        *(f16x8*)(ohp + pk_off(row, d)) = h;
    }
    if (out32) {
        float4 o0 = {r[0], r[1], r[2], r[3]};
        float4 o1 = {r[4], r[5], r[6], r[7]};
        *(float4*)(out32 + i) = o0;
        *(float4*)(out32 + i + 4) = o1;
    }
}

// ---------------- action head: softmax(X3[:, :8960] @ Wa + ba) --------------
__global__ __launch_bounds__(256) void action_kernel(
    const float* __restrict__ X3, const float* __restrict__ Wa,
    const float* __restrict__ ba, float* __restrict__ xact) {
    __shared__ float xs[SPLIT];
    __shared__ float red[256];
    const int row = blockIdx.x, t = threadIdx.x;
    const float* xr = X3 + (size_t)row * DH;
    for (int k = t * 4; k < SPLIT; k += 1024)
        *(float4*)&xs[k] = *(const float4*)(xr + k);
    __syncthreads();
    const int col = t & 63, kqq = t >> 6;
    float acc = 0.f;
    for (int k = kqq * 2240; k < (kqq + 1) * 2240; ++k)
        acc += xs[k] * Wa[(size_t)k * 64 + col];
    red[t] = acc;
    __syncthreads();
    if (t < 64) {
        float z = red[t] + red[t + 64] + red[t + 128] + red[t + 192] + ba[t];
        float mx = z;
        for (int off = 32; off; off >>= 1) mx = fmaxf(mx, __shfl_xor(mx, off));
        float e = expf(z - mx);
        float s = e;
        for (int off = 32; off; off >>= 1) s += __shfl_xor(s, off);
        xact[row * 64 + t] = e / s;
    }
}

// ---------------- selection head + final outputs ---------------------------
__global__ __launch_bounds__(256) void select_kernel(
    const float* __restrict__ X3, const float* __restrict__ Ws,
    const float* __restrict__ bs, const void* __restrict__ maskp,
    const float* __restrict__ u, const float* __restrict__ xact,
    float* __restrict__ out) {
    __shared__ float xs[256];
    __shared__ float psh[256];
    __shared__ float rr[4];
    __shared__ float bestv[4];
    __shared__ int besti[4];
    __shared__ int sIdx;
    __shared__ int smode;
    const int row = blockIdx.x, t = threadIdx.x;
    const int lane = t & 63, wid = t >> 6;

    // mask dtype detection: int32 {0,1} / bytes {0,1} / float {0.f,1.f}
    if (t < 64) {
        unsigned v = ((const unsigned*)maskp)[t];
        int okInt  = __all(v <= 1u);
        int okByte = __all((v & 0xFEFEFEFEu) == 0u);
        if (t == 0) smode = okInt ? 0 : (okByte ? 1 : 2);
    }
    xs[t] = X3[(size_t)row * DH + SPLIT + t];
    __syncthreads();

    bool mk;
    if (smode == 0)       mk = ((const int*)maskp)[row * 256 + t] != 0;
    else if (smode == 1)  mk = ((const unsigned char*)maskp)[row * 256 + t] != 0;
    else                  mk = ((const float*)maskp)[row * 256 + t] != 0.0f;

    float z = bs[t];
    for (int k = 0; k < 256; ++k)
        z += xs[k] * Ws[k * 256 + t];

    // softmax #1
    float v = z;
    for (int off = 32; off; off >>= 1) v = fmaxf(v, __shfl_xor(v, off));
    if (lane == 0) rr[wid] = v;
    __syncthreads();
    float m1 = fmaxf(fmaxf(rr[0], rr[1]), fmaxf(rr[2], rr[3]));
    __syncthreads();
    float e1 = expf(z - m1);
    v = e1;
    for (int off = 32; off; off >>= 1) v += __shfl_xor(v, off);
    if (lane == 0) rr[wid] = v;
    __syncthreads();
    float s1 = rr[0] + rr[1] + rr[2] + rr[3];
    __syncthreads();
    float p1 = e1 / s1;

    // mask, softmax #2
    float q = mk ? -1e9f : p1;
    v = q;
    for (int off = 32; off; off >>= 1) v = fmaxf(v, __shfl_xor(v, off));
    if (lane == 0) rr[wid] = v;
    __syncthreads();
    float m2 = fmaxf(fmaxf(rr[0], rr[1]), fmaxf(rr[2], rr[3]));
    __syncthreads();
    float e2 = expf(q - m2);
    v = e2;
    for (int off = 32; off; off >>= 1) v += __shfl_xor(v, off);
    if (lane == 0) rr[wid] = v;
    __syncthreads();
    float s2 = rr[0] + rr[1] + rr[2] + rr[3];
    float p2 = e2 / s2;
    psh[t] = p2;

    // gumbel scores + first-occurrence argmax
    float g = -logf(-logf(u[row * 256 + t]));
    float sc = mk ? -INFINITY : (logf(p2) + g);
    float bv = sc;
    int bi = t;
    for (int off = 32; off; off >>= 1) {
        float ov = __shfl_xor(bv, off);
        int oi = __shfl_xor(bi, off);
        if (ov > bv || (ov == bv && oi < bi)) { bv = ov; bi = oi; }
    }
    if (lane == 0) { bestv[wid] = bv; besti[wid] = bi; }
    __syncthreads();
    if (t == 0) {
        float fv = bestv[0];
        int fi = besti[0];
        for (int w = 1; w < 4; ++w)
            if (bestv[w] > fv || (bestv[w] == fv && besti[w] < fi)) {
                fv = bestv[w]; fi = besti[w];
            }
        sIdx = fi;
    }
    __syncthreads();
    const int idx = sIdx;
    const float sp = psh[idx];
    if (t < 64) out[row * 64 + t] = xact[row * 64 + t] * sp;
    if (t == 0) {
        out[256 * 64 + row * 2 + 0] = (float)(idx >> 4);
        out[256 * 64 + row * 2 + 1] = (float)(idx & 15);
    }
}

// ---------------------------------------------------------------------------
extern "C" void kernel_launch(void* const* d_in, const int* in_sizes, int n_in,
                              void* d_out, int out_size, void* d_ws, size_t ws_size,
                              hipStream_t stream) {
    const float* s  = (const float*)d_in[0];
    const void*  mask = d_in[1];
    const float* u  = (const float*)d_in[2];
    const float* W1 = (const float*)d_in[3];
    const float* b1 = (const float*)d_in[4];
    const float* W2 = (const float*)d_in[5];
    const float* b2 = (const float*)d_in[6];
    const float* W3 = (const float*)d_in[7];
    const float* b3 = (const float*)d_in[8];
    const float* Wa = (const float*)d_in[9];
    const float* ba = (const float*)d_in[10];
    const float* Ws = (const float*)d_in[11];
    const float* bs = (const float*)d_in[12];
    float* out = (float*)d_out;
    char* ws = (char*)d_ws;

    // workspace map:
    //   [0,        8,388,608)  A0p packed f16 (K=16384)   (reused by X2p)
    //   [8388608, 13,107,200)  X1p packed f16 (K=9216)
    //   [13107200,22,544,384)  X3 f32 [256][9216]
    //   [22544384,22,609,920)  XA f32 [256][64]
    //   [22609920, ...)        P  f16 [S][256][9216]  (4.72 MB/plane)
    char*  A0p = ws + 0;
    char*  X1p = ws + 8388608;
    char*  X2p = ws + 0;                   // reuses dead A0p
    float* X3  = (float*)(ws + 13107200);
    float* XA  = (float*)(ws + 22544384);
    f16*   P   = (f16*)(ws + 22609920);

    const size_t pbytes = 4718592ull;      // one f16 splitK plane
    int yshift = (ws_size >= 22609920ull + 8 * pbytes) ? 3 : 2;
    const int S = 1 << yshift;

    cvt_kernel<<<2048, 256, 0, stream>>>(s, A0p);

    const int nblk = 72 << yshift;         // 576 @ S=8; y = bid & (S-1)
    gemm_kernel<<<nblk, 256, 0, stream>>>(A0p, 16384, 16384 / S, yshift, W1, P);
    reduce_kernel<<<1152, 256, 0, stream>>>(P, S, b1, X1p, nullptr);
    gemm_kernel<<<nblk, 256, 0, stream>>>(X1p, DH, DH / S, yshift, W2, P);
    reduce_kernel<<<1152, 256, 0, stream>>>(P, S, b2, X2p, nullptr);
    gemm_kernel<<<nblk, 256, 0, stream>>>(X2p, DH, DH / S, yshift, W3, P);
    reduce_kernel<<<1152, 256, 0, stream>>>(P, S, b3, nullptr, X3);

    action_kernel<<<256, 256, 0, stream>>>(X3, Wa, ba, XA);
    select_kernel<<<256, 256, 0, stream>>>(X3, Ws, bs, mask, u, XA, out);
}

// Round 23
// 509.764 us; speedup vs baseline: 1.1926x; 1.1926x over previous
//
#include <hip/hip_runtime.h>
#include <hip/hip_fp16.h>

// ---------------------------------------------------------------------------
// MLPForwardPolicy — r20 champion GEMM byte-identical; ONLY change: S=8 -> 16.
//
// r22 lesson (3rd strike): reg-transit A always loses to all-DMA; abandoned.
// r20 runs 576 blocks on 512 slots (1.125 rounds) -> worst-case makespan ~2
// block-lifetimes. S=16: 1152 shorter blocks (ns 32/18) = 2.25 rounds ->
// better load balance (r11>r15 precedent). P = 16 f16 planes = 75.5 MB
// (22.6+75.5 = 98.1 MB — exact footprint proven in r2/r3). Reduce +12 us.
// Ranking: r20=499 r19=514 r21=535 r16/r18=561 r11=592 r7=606 r22=608.
// ---------------------------------------------------------------------------

typedef _Float16 f16;
typedef _Float16 f16x4 __attribute__((ext_vector_type(4)));
typedef _Float16 f16x8 __attribute__((ext_vector_type(8)));
typedef float f32x4 __attribute__((ext_vector_type(4)));

#define DH 9216
#define SPLIT 8960

__device__ __forceinline__ void gload16(const void* g, void* l) {
    __builtin_amdgcn_global_load_lds(
        (const __attribute__((address_space(1))) void*)g,
        (__attribute__((address_space(3))) void*)l, 16, 0, 0);
}

// packed-granule byte offset for element (row, k)
__device__ __forceinline__ size_t pk_off(int row, int k) {
    int tk = k >> 5, q = (k >> 3) & 3;
    int mhalf = row >> 7, wmA = (row >> 6) & 1, ri = (row >> 4) & 3, lc = row & 15;
    int h = (wmA << 8) | (ri << 6) | (q << 4) | lc;
    return (size_t)(tk * 2 + mhalf) * 8192 + (size_t)h * 16;
}

// ---------------- f32 -> packed f16 granules (for A0) ----------------
__global__ void cvt_kernel(const float* __restrict__ in, char* __restrict__ outp) {
    int idx = blockIdx.x * blockDim.x + threadIdx.x;   // [0, 524288)
    int row = idx >> 11;
    int k8  = (idx & 2047) << 3;
    const float* src = in + ((size_t)row << 14) + k8;
    f16x8 h;
#pragma unroll
    for (int j = 0; j < 8; ++j) h[j] = (_Float16)src[j];
    *(f16x8*)(outp + pk_off(row, k8)) = h;
}

// ---------------- streaming GEMM: P[y] = A[256,Kh] @ W[Kh, 128-col] ---------
// linear grid 72<<yshift blocks of 256 threads; y = bid & (S-1)
// n0 = (bid >> yshift) * 128
// 4 waves 2x2: wave(wm,wn) owns rows wm*128..+128 x cols n0+wn*64..+64
__global__ __launch_bounds__(256, 2) void gemm_kernel(
    const char* __restrict__ Ap, int K, int Kh, int yshift,
    const float* __restrict__ W,
    f16* __restrict__ P)   // [S][256][9216] f16 partials
{
    __shared__ __align__(16) char lds[2][32768];   // [W 16K][A 16K] x2
    const int bid  = blockIdx.x;
    const int y    = bid & ((1 << yshift) - 1);
    const int n0   = (bid >> yshift) << 7;
    const int tid  = threadIdx.x;
    const int lane = tid & 63;
    const int wid  = tid >> 6;
    const int wm   = wid >> 1, wn = wid & 1;
    const int kbase = y * Kh;
    const int ns   = Kh >> 5;                     // BK = 32 (32 or 18)

    f32x4 acc[8][4] = {};

    // ---- hoisted W DMA source pointers ----
    const float* wsrc0;
    const float* wsrc1;
    const float* wsrc2;
    const float* wsrc3;
    {
        int g0 = tid,      k0 = g0 >> 5, c0 = (g0 & 31) ^ ((5 * (k0 >> 3)) & 31);
        int g1 = tid + 256, k1 = g1 >> 5, c1 = (g1 & 31) ^ ((5 * (k1 >> 3)) & 31);
        int g2 = tid + 512, k2 = g2 >> 5, c2 = (g2 & 31) ^ ((5 * (k2 >> 3)) & 31);
        int g3 = tid + 768, k3 = g3 >> 5, c3 = (g3 & 31) ^ ((5 * (k3 >> 3)) & 31);
        wsrc0 = W + (size_t)(kbase + k0) * DH + n0 + (c0 << 2);
        wsrc1 = W + (size_t)(kbase + k1) * DH + n0 + (c1 << 2);
        wsrc2 = W + (size_t)(kbase + k2) * DH + n0 + (c2 << 2);
        wsrc3 = W + (size_t)(kbase + k3) * DH + n0 + (c3 << 2);
    }
    // packed A: stage t = 16 KB contiguous (both m-halves) at ap + t*16384
    const char* ap = Ap + (size_t)(y * (Kh >> 5) * 2) * 8192;

    auto issue = [&](int slot) {      // 8 DMA instr/thread; advance 1 stage
        char* dst = &lds[slot][0];
        gload16(wsrc0, dst + (size_t)tid * 16);          wsrc0 += 32 * DH;
        gload16(wsrc1, dst + (size_t)(tid + 256) * 16);  wsrc1 += 32 * DH;
        gload16(wsrc2, dst + (size_t)(tid + 512) * 16);  wsrc2 += 32 * DH;
        gload16(wsrc3, dst + (size_t)(tid + 768) * 16);  wsrc3 += 32 * DH;
        gload16(ap + (size_t)tid * 16,         dst + 16384 + (size_t)tid * 16);
        gload16(ap + (size_t)tid * 16 + 4096,  dst + 16384 + (size_t)tid * 16 + 4096);
        gload16(ap + (size_t)tid * 16 + 8192,  dst + 16384 + (size_t)tid * 16 + 8192);
        gload16(ap + (size_t)tid * 16 + 12288, dst + 16384 + (size_t)tid * 16 + 12288);
        ap += 16384;
    };

    const int q  = lane >> 4;
    const int lc = lane & 15;
    auto step = [&](int slot) {
        const float* wl = (const float*)&lds[slot][0];
        const f16*   al = (const f16*)&lds[slot][16384];
        f16x8 af[8], bf[4];
#pragma unroll
        for (int ri8 = 0; ri8 < 8; ++ri8) {
            int off = (wm << 12) + (((ri8 >> 2) << 8) | ((ri8 & 3) << 6)) + lane;
            af[ri8] = *(const f16x8*)(al + ((size_t)off << 3));
        }
        const int wbase = (q << 10) + (lc & 3);
#pragma unroll
        for (int ni = 0; ni < 4; ++ni) {
            int p = ((wn << 4) + (ni << 2) + (lc >> 2)) ^ (5 * q);
            int fi = wbase + ((p & 31) << 2);
            f16x8 b;
#pragma unroll
            for (int j = 0; j < 8; ++j)
                b[j] = (_Float16)wl[fi + (j << 7)];
            bf[ni] = b;
        }
#pragma unroll
        for (int ri = 0; ri < 8; ++ri)
#pragma unroll
            for (int ni = 0; ni < 4; ++ni)
                acc[ri][ni] = __builtin_amdgcn_mfma_f32_16x16x32_f16(
                    af[ri], bf[ni], acc[ri][ni], 0, 0, 0);
    };

    issue(0);
    issue(1);
    __builtin_amdgcn_sched_barrier(0);

    for (int t = 0; t < ns; ++t) {
        if (t + 1 < ns) asm volatile("s_waitcnt vmcnt(8)" ::: "memory");
        else            asm volatile("s_waitcnt vmcnt(0)" ::: "memory");
        __builtin_amdgcn_sched_barrier(0);
        __builtin_amdgcn_s_barrier();
        __builtin_amdgcn_sched_barrier(0);
        step(t & 1);
        __builtin_amdgcn_sched_barrier(0);
        asm volatile("s_waitcnt lgkmcnt(0)" ::: "memory");
        __builtin_amdgcn_sched_barrier(0);
        __builtin_amdgcn_s_barrier();
        __builtin_amdgcn_sched_barrier(0);
        if (t + 2 < ns) {
            issue(t & 1);
            __builtin_amdgcn_sched_barrier(0);
        }
    }

    // epilogue: D layout col=lane&15, row=(lane>>4)*4+reg  [m89-verified]
    f16* Pb = P + (size_t)y * (256 * DH);
#pragma unroll
    for (int ri = 0; ri < 8; ++ri) {
        int row = wm * 128 + ri * 16 + (q << 2);
#pragma unroll
        for (int ni = 0; ni < 4; ++ni) {
            int col = n0 + wn * 64 + ni * 16 + lc;
#pragma unroll
            for (int rg = 0; rg < 4; ++rg)
                Pb[(size_t)(row + rg) * DH + col] = (_Float16)acc[ri][ni][rg];
        }
    }
}

// ---------------- splitK reduce (f16 partials) + bias + relu ----------------
// ohp != null: write PACKED granules (pk_off layout)
__global__ __launch_bounds__(256) void reduce_kernel(
    const f16* __restrict__ P, int S,
    const float* __restrict__ bias,
    char* __restrict__ ohp, float* __restrict__ out32) {
    const size_t n = 256 * DH;
    const size_t i = ((size_t)blockIdx.x * 256 + threadIdx.x) * 8;
    if (i >= n) return;
    const int row = (int)(i / DH);
    const int d   = (int)(i % DH);
    float r[8];
    {
        float4 b0 = *(const float4*)(bias + d);
        float4 b1 = *(const float4*)(bias + d + 4);
        r[0] = b0.x; r[1] = b0.y; r[2] = b0.z; r[3] = b0.w;
        r[4] = b1.x; r[5] = b1.y; r[6] = b1.z; r[7] = b1.w;
    }
    for (int j = 0; j < S; ++j) {
        f16x8 v = *(const f16x8*)(P + (size_t)j * n + i);
#pragma unroll
        for (int e = 0; e < 8; ++e) r[e] += (float)v[e];
    }
#pragma unroll
    for (int e = 0; e < 8; ++e) r[e] = fmaxf(r[e], 0.f);
    if (ohp) {
        f16x8 h;
#pragma unroll
        for (int e = 0; e < 8; ++e) h[e] = (_Float16)r[e];
        *(f16x8*)(ohp + pk_off(row, d)) = h;
    }
    if (out32) {
        float4 o0 = {r[0], r[1], r[2], r[3]};
        float4 o1 = {r[4], r[5], r[6], r[7]};
        *(float4*)(out32 + i) = o0;
        *(float4*)(out32 + i + 4) = o1;
    }
}

// ---------------- action head: softmax(X3[:, :8960] @ Wa + ba) --------------
__global__ __launch_bounds__(256) void action_kernel(
    const float* __restrict__ X3, const float* __restrict__ Wa,
    const float* __restrict__ ba, float* __restrict__ xact) {
    __shared__ float xs[SPLIT];
    __shared__ float red[256];
    const int row = blockIdx.x, t = threadIdx.x;
    const float* xr = X3 + (size_t)row * DH;
    for (int k = t * 4; k < SPLIT; k += 1024)
        *(float4*)&xs[k] = *(const float4*)(xr + k);
    __syncthreads();
    const int col = t & 63, kqq = t >> 6;
    float acc = 0.f;
    for (int k = kqq * 2240; k < (kqq + 1) * 2240; ++k)
        acc += xs[k] * Wa[(size_t)k * 64 + col];
    red[t] = acc;
    __syncthreads();
    if (t < 64) {
        float z = red[t] + red[t + 64] + red[t + 128] + red[t + 192] + ba[t];
        float mx = z;
        for (int off = 32; off; off >>= 1) mx = fmaxf(mx, __shfl_xor(mx, off));
        float e = expf(z - mx);
        float s = e;
        for (int off = 32; off; off >>= 1) s += __shfl_xor(s, off);
        xact[row * 64 + t] = e / s;
    }
}

// ---------------- selection head + final outputs ---------------------------
__global__ __launch_bounds__(256) void select_kernel(
    const float* __restrict__ X3, const float* __restrict__ Ws,
    const float* __restrict__ bs, const void* __restrict__ maskp,
    const float* __restrict__ u, const float* __restrict__ xact,
    float* __restrict__ out) {
    __shared__ float xs[256];
    __shared__ float psh[256];
    __shared__ float rr[4];
    __shared__ float bestv[4];
    __shared__ int besti[4];
    __shared__ int sIdx;
    __shared__ int smode;
    const int row = blockIdx.x, t = threadIdx.x;
    const int lane = t & 63, wid = t >> 6;

    // mask dtype detection: int32 {0,1} / bytes {0,1} / float {0.f,1.f}
    if (t < 64) {
        unsigned v = ((const unsigned*)maskp)[t];
        int okInt  = __all(v <= 1u);
        int okByte = __all((v & 0xFEFEFEFEu) == 0u);
        if (t == 0) smode = okInt ? 0 : (okByte ? 1 : 2);
    }
    xs[t] = X3[(size_t)row * DH + SPLIT + t];
    __syncthreads();

    bool mk;
    if (smode == 0)       mk = ((const int*)maskp)[row * 256 + t] != 0;
    else if (smode == 1)  mk = ((const unsigned char*)maskp)[row * 256 + t] != 0;
    else                  mk = ((const float*)maskp)[row * 256 + t] != 0.0f;

    float z = bs[t];
    for (int k = 0; k < 256; ++k)
        z += xs[k] * Ws[k * 256 + t];

    // softmax #1
    float v = z;
    for (int off = 32; off; off >>= 1) v = fmaxf(v, __shfl_xor(v, off));
    if (lane == 0) rr[wid] = v;
    __syncthreads();
    float m1 = fmaxf(fmaxf(rr[0], rr[1]), fmaxf(rr[2], rr[3]));
    __syncthreads();
    float e1 = expf(z - m1);
    v = e1;
    for (int off = 32; off; off >>= 1) v += __shfl_xor(v, off);
    if (lane == 0) rr[wid] = v;
    __syncthreads();
    float s1 = rr[0] + rr[1] + rr[2] + rr[3];
    __syncthreads();
    float p1 = e1 / s1;

    // mask, softmax #2
    float q = mk ? -1e9f : p1;
    v = q;
    for (int off = 32; off; off >>= 1) v = fmaxf(v, __shfl_xor(v, off));
    if (lane == 0) rr[wid] = v;
    __syncthreads();
    float m2 = fmaxf(fmaxf(rr[0], rr[1]), fmaxf(rr[2], rr[3]));
    __syncthreads();
    float e2 = expf(q - m2);
    v = e2;
    for (int off = 32; off; off >>= 1) v += __shfl_xor(v, off);
    if (lane == 0) rr[wid] = v;
    __syncthreads();
    float s2 = rr[0] + rr[1] + rr[2] + rr[3];
    float p2 = e2 / s2;
    psh[t] = p2;

    // gumbel scores + first-occurrence argmax
    float g = -logf(-logf(u[row * 256 + t]));
    float sc = mk ? -INFINITY : (logf(p2) + g);
    float bv = sc;
    int bi = t;
    for (int off = 32; off; off >>= 1) {
        float ov = __shfl_xor(bv, off);
        int oi = __shfl_xor(bi, off);
        if (ov > bv || (ov == bv && oi < bi)) { bv = ov; bi = oi; }
    }
    if (lane == 0) { bestv[wid] = bv; besti[wid] = bi; }
    __syncthreads();
    if (t == 0) {
        float fv = bestv[0];
        int fi = besti[0];
        for (int w = 1; w < 4; ++w)
            if (bestv[w] > fv || (bestv[w] == fv && besti[w] < fi)) {
                fv = bestv[w]; fi = besti[w];
            }
        sIdx = fi;
    }
    __syncthreads();
    const int idx = sIdx;
    const float sp = psh[idx];
    if (t < 64) out[row * 64 + t] = xact[row * 64 + t] * sp;
    if (t == 0) {
        out[256 * 64 + row * 2 + 0] = (float)(idx >> 4);
        out[256 * 64 + row * 2 + 1] = (float)(idx & 15);
    }
}

// ---------------------------------------------------------------------------
extern "C" void kernel_launch(void* const* d_in, const int* in_sizes, int n_in,
                              void* d_out, int out_size, void* d_ws, size_t ws_size,
                              hipStream_t stream) {
    const float* s  = (const float*)d_in[0];
    const void*  mask = d_in[1];
    const float* u  = (const float*)d_in[2];
    const float* W1 = (const float*)d_in[3];
    const float* b1 = (const float*)d_in[4];
    const float* W2 = (const float*)d_in[5];
    const float* b2 = (const float*)d_in[6];
    const float* W3 = (const float*)d_in[7];
    const float* b3 = (const float*)d_in[8];
    const float* Wa = (const float*)d_in[9];
    const float* ba = (const float*)d_in[10];
    const float* Ws = (const float*)d_in[11];
    const float* bs = (const float*)d_in[12];
    float* out = (float*)d_out;
    char* ws = (char*)d_ws;

    // workspace map:
    //   [0,        8,388,608)  A0p packed f16 (K=16384)   (reused by X2p)
    //   [8388608, 13,107,200)  X1p packed f16 (K=9216)
    //   [13107200,22,544,384)  X3 f32 [256][9216]
    //   [22544384,22,609,920)  XA f32 [256][64]
    //   [22609920, ...)        P  f16 [S][256][9216]  (4.72 MB/plane; S=16 -> 75.5 MB)
    char*  A0p = ws + 0;
    char*  X1p = ws + 8388608;
    char*  X2p = ws + 0;                   // reuses dead A0p
    float* X3  = (float*)(ws + 13107200);
    float* XA  = (float*)(ws + 22544384);
    f16*   P   = (f16*)(ws + 22609920);

    const size_t pbytes = 4718592ull;      // one f16 splitK plane
    int yshift = (ws_size >= 22609920ull + 16 * pbytes) ? 4 : 3;
    const int S = 1 << yshift;             // 16 (98.1 MB footprint, proven in r2/r3)

    cvt_kernel<<<2048, 256, 0, stream>>>(s, A0p);

    const int nblk = 72 << yshift;         // 1152 @ S=16; y = bid & (S-1)
    gemm_kernel<<<nblk, 256, 0, stream>>>(A0p, 16384, 16384 / S, yshift, W1, P);
    reduce_kernel<<<1152, 256, 0, stream>>>(P, S, b1, X1p, nullptr);
    gemm_kernel<<<nblk, 256, 0, stream>>>(X1p, DH, DH / S, yshift, W2, P);
    reduce_kernel<<<1152, 256, 0, stream>>>(P, S, b2, X2p, nullptr);
    gemm_kernel<<<nblk, 256, 0, stream>>>(X2p, DH, DH / S, yshift, W3, P);
    reduce_kernel<<<1152, 256, 0, stream>>>(P, S, b3, nullptr, X3);

    action_kernel<<<256, 256, 0, stream>>>(X3, Wa, ba, XA);
    select_kernel<<<256, 256, 0, stream>>>(X3, Ws, bs, mask, u, XA, out);
}

// Round 24
// 495.251 us; speedup vs baseline: 1.2275x; 1.0293x over previous
//
#include <hip/hip_runtime.h>
#include <hip/hip_fp16.h>

// ---------------------------------------------------------------------------
// MLPForwardPolicy — r20 champion GEMM (S=8) + fused tail:
// reduce3+action+select in ONE kernel (256 blocks = 1 row each; row reduced
// into 36 KB LDS, action kq-split dot, xact in LDS, selection + outputs).
// Removes X3 (9.4 MB) & XA round-trips and 2 launches; math byte-identical.
// r23 lesson: S=16 load-balance null (-2%); byte/balance axes exhausted.
// Ranking: r20=499 r23=510 r19=514 r21=535 r16/r18=561 r11=592.
// ---------------------------------------------------------------------------

typedef _Float16 f16;
typedef _Float16 f16x4 __attribute__((ext_vector_type(4)));
typedef _Float16 f16x8 __attribute__((ext_vector_type(8)));
typedef float f32x4 __attribute__((ext_vector_type(4)));

#define DH 9216
#define SPLIT 8960

__device__ __forceinline__ void gload16(const void* g, void* l) {
    __builtin_amdgcn_global_load_lds(
        (const __attribute__((address_space(1))) void*)g,
        (__attribute__((address_space(3))) void*)l, 16, 0, 0);
}

// packed-granule byte offset for element (row, k)
__device__ __forceinline__ size_t pk_off(int row, int k) {
    int tk = k >> 5, q = (k >> 3) & 3;
    int mhalf = row >> 7, wmA = (row >> 6) & 1, ri = (row >> 4) & 3, lc = row & 15;
    int h = (wmA << 8) | (ri << 6) | (q << 4) | lc;
    return (size_t)(tk * 2 + mhalf) * 8192 + (size_t)h * 16;
}

// ---------------- f32 -> packed f16 granules (for A0) ----------------
__global__ void cvt_kernel(const float* __restrict__ in, char* __restrict__ outp) {
    int idx = blockIdx.x * blockDim.x + threadIdx.x;   // [0, 524288)
    int row = idx >> 11;
    int k8  = (idx & 2047) << 3;
    const float* src = in + ((size_t)row << 14) + k8;
    f16x8 h;
#pragma unroll
    for (int j = 0; j < 8; ++j) h[j] = (_Float16)src[j];
    *(f16x8*)(outp + pk_off(row, k8)) = h;
}

// ---------------- streaming GEMM: P[y] = A[256,Kh] @ W[Kh, 128-col] ---------
// linear grid 72<<yshift blocks of 256 threads; y = bid & (S-1)
// n0 = (bid >> yshift) * 128
// 4 waves 2x2: wave(wm,wn) owns rows wm*128..+128 x cols n0+wn*64..+64
__global__ __launch_bounds__(256, 2) void gemm_kernel(
    const char* __restrict__ Ap, int K, int Kh, int yshift,
    const float* __restrict__ W,
    f16* __restrict__ P)   // [S][256][9216] f16 partials
{
    __shared__ __align__(16) char lds[2][32768];   // [W 16K][A 16K] x2
    const int bid  = blockIdx.x;
    const int y    = bid & ((1 << yshift) - 1);
    const int n0   = (bid >> yshift) << 7;
    const int tid  = threadIdx.x;
    const int lane = tid & 63;
    const int wid  = tid >> 6;
    const int wm   = wid >> 1, wn = wid & 1;
    const int kbase = y * Kh;
    const int ns   = Kh >> 5;                     // BK = 32 (64 or 36)

    f32x4 acc[8][4] = {};

    // ---- hoisted W DMA source pointers ----
    const float* wsrc0;
    const float* wsrc1;
    const float* wsrc2;
    const float* wsrc3;
    {
        int g0 = tid,      k0 = g0 >> 5, c0 = (g0 & 31) ^ ((5 * (k0 >> 3)) & 31);
        int g1 = tid + 256, k1 = g1 >> 5, c1 = (g1 & 31) ^ ((5 * (k1 >> 3)) & 31);
        int g2 = tid + 512, k2 = g2 >> 5, c2 = (g2 & 31) ^ ((5 * (k2 >> 3)) & 31);
        int g3 = tid + 768, k3 = g3 >> 5, c3 = (g3 & 31) ^ ((5 * (k3 >> 3)) & 31);
        wsrc0 = W + (size_t)(kbase + k0) * DH + n0 + (c0 << 2);
        wsrc1 = W + (size_t)(kbase + k1) * DH + n0 + (c1 << 2);
        wsrc2 = W + (size_t)(kbase + k2) * DH + n0 + (c2 << 2);
        wsrc3 = W + (size_t)(kbase + k3) * DH + n0 + (c3 << 2);
    }
    // packed A: stage t = 16 KB contiguous (both m-halves) at ap + t*16384
    const char* ap = Ap + (size_t)(y * (Kh >> 5) * 2) * 8192;

    auto issue = [&](int slot) {      // 8 DMA instr/thread; advance 1 stage
        char* dst = &lds[slot][0];
        gload16(wsrc0, dst + (size_t)tid * 16);          wsrc0 += 32 * DH;
        gload16(wsrc1, dst + (size_t)(tid + 256) * 16);  wsrc1 += 32 * DH;
        gload16(wsrc2, dst + (size_t)(tid + 512) * 16);  wsrc2 += 32 * DH;
        gload16(wsrc3, dst + (size_t)(tid + 768) * 16);  wsrc3 += 32 * DH;
        gload16(ap + (size_t)tid * 16,         dst + 16384 + (size_t)tid * 16);
        gload16(ap + (size_t)tid * 16 + 4096,  dst + 16384 + (size_t)tid * 16 + 4096);
        gload16(ap + (size_t)tid * 16 + 8192,  dst + 16384 + (size_t)tid * 16 + 8192);
        gload16(ap + (size_t)tid * 16 + 12288, dst + 16384 + (size_t)tid * 16 + 12288);
        ap += 16384;
    };

    const int q  = lane >> 4;
    const int lc = lane & 15;
    auto step = [&](int slot) {
        const float* wl = (const float*)&lds[slot][0];
        const f16*   al = (const f16*)&lds[slot][16384];
        f16x8 af[8], bf[4];
#pragma unroll
        for (int ri8 = 0; ri8 < 8; ++ri8) {
            int off = (wm << 12) + (((ri8 >> 2) << 8) | ((ri8 & 3) << 6)) + lane;
            af[ri8] = *(const f16x8*)(al + ((size_t)off << 3));
        }
        const int wbase = (q << 10) + (lc & 3);
#pragma unroll
        for (int ni = 0; ni < 4; ++ni) {
            int p = ((wn << 4) + (ni << 2) + (lc >> 2)) ^ (5 * q);
            int fi = wbase + ((p & 31) << 2);
            f16x8 b;
#pragma unroll
            for (int j = 0; j < 8; ++j)
                b[j] = (_Float16)wl[fi + (j << 7)];
            bf[ni] = b;
        }
#pragma unroll
        for (int ri = 0; ri < 8; ++ri)
#pragma unroll
            for (int ni = 0; ni < 4; ++ni)
                acc[ri][ni] = __builtin_amdgcn_mfma_f32_16x16x32_f16(
                    af[ri], bf[ni], acc[ri][ni], 0, 0, 0);
    };

    issue(0);
    issue(1);
    __builtin_amdgcn_sched_barrier(0);

    for (int t = 0; t < ns; ++t) {
        if (t + 1 < ns) asm volatile("s_waitcnt vmcnt(8)" ::: "memory");
        else            asm volatile("s_waitcnt vmcnt(0)" ::: "memory");
        __builtin_amdgcn_sched_barrier(0);
        __builtin_amdgcn_s_barrier();
        __builtin_amdgcn_sched_barrier(0);
        step(t & 1);
        __builtin_amdgcn_sched_barrier(0);
        asm volatile("s_waitcnt lgkmcnt(0)" ::: "memory");
        __builtin_amdgcn_sched_barrier(0);
        __builtin_amdgcn_s_barrier();
        __builtin_amdgcn_sched_barrier(0);
        if (t + 2 < ns) {
            issue(t & 1);
            __builtin_amdgcn_sched_barrier(0);
        }
    }

    // epilogue: D layout col=lane&15, row=(lane>>4)*4+reg  [m89-verified]
    f16* Pb = P + (size_t)y * (256 * DH);
#pragma unroll
    for (int ri = 0; ri < 8; ++ri) {
        int row = wm * 128 + ri * 16 + (q << 2);
#pragma unroll
        for (int ni = 0; ni < 4; ++ni) {
            int col = n0 + wn * 64 + ni * 16 + lc;
#pragma unroll
            for (int rg = 0; rg < 4; ++rg)
                Pb[(size_t)(row + rg) * DH + col] = (_Float16)acc[ri][ni][rg];
        }
    }
}

// ---------------- splitK reduce (f16 partials) + bias + relu -> packed X ----
__global__ __launch_bounds__(256) void reduce_kernel(
    const f16* __restrict__ P, int S,
    const float* __restrict__ bias,
    char* __restrict__ ohp) {
    const size_t n = 256 * DH;
    const size_t i = ((size_t)blockIdx.x * 256 + threadIdx.x) * 8;
    if (i >= n) return;
    const int row = (int)(i / DH);
    const int d   = (int)(i % DH);
    float r[8];
    {
        float4 b0 = *(const float4*)(bias + d);
        float4 b1 = *(const float4*)(bias + d + 4);
        r[0] = b0.x; r[1] = b0.y; r[2] = b0.z; r[3] = b0.w;
        r[4] = b1.x; r[5] = b1.y; r[6] = b1.z; r[7] = b1.w;
    }
    for (int j = 0; j < S; ++j) {
        f16x8 v = *(const f16x8*)(P + (size_t)j * n + i);
#pragma unroll
        for (int e = 0; e < 8; ++e) r[e] += (float)v[e];
    }
#pragma unroll
    for (int e = 0; e < 8; ++e) r[e] = fmaxf(r[e], 0.f);
    f16x8 h;
#pragma unroll
    for (int e = 0; e < 8; ++e) h[e] = (_Float16)r[e];
    *(f16x8*)(ohp + pk_off(row, d)) = h;
}

// ---------------- fused tail: reduce3 + action + selection -----------------
// 256 blocks (1 row each) x 256 threads; row reduced into LDS (36 KB f32).
__global__ __launch_bounds__(256) void tail_kernel(
    const f16* __restrict__ P, int S, const float* __restrict__ b3,
    const float* __restrict__ Wa, const float* __restrict__ ba,
    const float* __restrict__ Ws, const float* __restrict__ bs,
    const void* __restrict__ maskp, const float* __restrict__ u,
    float* __restrict__ out) {
    __shared__ float xrow[DH];
    __shared__ float red[256];
    __shared__ float xact[64];
    __shared__ float psh[256];
    __shared__ float rr[4];
    __shared__ float bestv[4];
    __shared__ int besti[4];
    __shared__ int sIdx;
    __shared__ int smode;
    const int row = blockIdx.x, t = threadIdx.x;
    const int lane = t & 63, wid = t >> 6;
    const size_t n = 256 * DH;

    // mask dtype detection: int32 {0,1} / bytes {0,1} / float {0.f,1.f}
    if (t < 64) {
        unsigned v = ((const unsigned*)maskp)[t];
        int okInt  = __all(v <= 1u);
        int okByte = __all((v & 0xFEFEFEFEu) == 0u);
        if (t == 0) smode = okInt ? 0 : (okByte ? 1 : 2);
    }

    // reduce this row's S f16 partials + bias + relu -> xrow (f32)
    for (int base = t * 8; base < DH; base += 2048) {
        float r[8];
        float4 b0 = *(const float4*)(b3 + base);
        float4 b1 = *(const float4*)(b3 + base + 4);
        r[0] = b0.x; r[1] = b0.y; r[2] = b0.z; r[3] = b0.w;
        r[4] = b1.x; r[5] = b1.y; r[6] = b1.z; r[7] = b1.w;
        const size_t idx = (size_t)row * DH + base;
        for (int j = 0; j < S; ++j) {
            f16x8 v = *(const f16x8*)(P + (size_t)j * n + idx);
#pragma unroll
            for (int e = 0; e < 8; ++e) r[e] += (float)v[e];
        }
#pragma unroll
        for (int e = 0; e < 8; ++e) xrow[base + e] = fmaxf(r[e], 0.f);
    }
    __syncthreads();

    // ---- action head: softmax(xrow[:8960] @ Wa + ba) -> xact (LDS) ----
    {
        const int col = t & 63, kqq = t >> 6;
        float acc = 0.f;
        for (int k = kqq * 2240; k < (kqq + 1) * 2240; ++k)
            acc += xrow[k] * Wa[(size_t)k * 64 + col];
        red[t] = acc;
        __syncthreads();
        if (t < 64) {
            float z = red[t] + red[t + 64] + red[t + 128] + red[t + 192] + ba[t];
            float mx = z;
            for (int off = 32; off; off >>= 1) mx = fmaxf(mx, __shfl_xor(mx, off));
            float e = expf(z - mx);
            float s = e;
            for (int off = 32; off; off >>= 1) s += __shfl_xor(s, off);
            xact[t] = e / s;
        }
        __syncthreads();
    }

    // ---- selection head ----
    bool mk;
    if (smode == 0)       mk = ((const int*)maskp)[row * 256 + t] != 0;
    else if (smode == 1)  mk = ((const unsigned char*)maskp)[row * 256 + t] != 0;
    else                  mk = ((const float*)maskp)[row * 256 + t] != 0.0f;

    float z = bs[t];
    for (int k = 0; k < 256; ++k)
        z += xrow[SPLIT + k] * Ws[k * 256 + t];

    // softmax #1
    float v = z;
    for (int off = 32; off; off >>= 1) v = fmaxf(v, __shfl_xor(v, off));
    if (lane == 0) rr[wid] = v;
    __syncthreads();
    float m1 = fmaxf(fmaxf(rr[0], rr[1]), fmaxf(rr[2], rr[3]));
    __syncthreads();
    float e1 = expf(z - m1);
    v = e1;
    for (int off = 32; off; off >>= 1) v += __shfl_xor(v, off);
    if (lane == 0) rr[wid] = v;
    __syncthreads();
    float s1 = rr[0] + rr[1] + rr[2] + rr[3];
    __syncthreads();
    float p1 = e1 / s1;

    // mask, softmax #2
    float q = mk ? -1e9f : p1;
    v = q;
    for (int off = 32; off; off >>= 1) v = fmaxf(v, __shfl_xor(v, off));
    if (lane == 0) rr[wid] = v;
    __syncthreads();
    float m2 = fmaxf(fmaxf(rr[0], rr[1]), fmaxf(rr[2], rr[3]));
    __syncthreads();
    float e2 = expf(q - m2);
    v = e2;
    for (int off = 32; off; off >>= 1) v += __shfl_xor(v, off);
    if (lane == 0) rr[wid] = v;
    __syncthreads();
    float s2 = rr[0] + rr[1] + rr[2] + rr[3];
    float p2 = e2 / s2;
    psh[t] = p2;

    // gumbel scores + first-occurrence argmax
    float g = -logf(-logf(u[row * 256 + t]));
    float sc = mk ? -INFINITY : (logf(p2) + g);
    float bv = sc;
    int bi = t;
    for (int off = 32; off; off >>= 1) {
        float ov = __shfl_xor(bv, off);
        int oi = __shfl_xor(bi, off);
        if (ov > bv || (ov == bv && oi < bi)) { bv = ov; bi = oi; }
    }
    if (lane == 0) { bestv[wid] = bv; besti[wid] = bi; }
    __syncthreads();
    if (t == 0) {
        float fv = bestv[0];
        int fi = besti[0];
        for (int w = 1; w < 4; ++w)
            if (bestv[w] > fv || (bestv[w] == fv && besti[w] < fi)) {
                fv = bestv[w]; fi = besti[w];
            }
        sIdx = fi;
    }
    __syncthreads();
    const int idx = sIdx;
    const float sp = psh[idx];
    if (t < 64) out[row * 64 + t] = xact[t] * sp;
    if (t == 0) {
        out[256 * 64 + row * 2 + 0] = (float)(idx >> 4);
        out[256 * 64 + row * 2 + 1] = (float)(idx & 15);
    }
}

// ---------------------------------------------------------------------------
extern "C" void kernel_launch(void* const* d_in, const int* in_sizes, int n_in,
                              void* d_out, int out_size, void* d_ws, size_t ws_size,
                              hipStream_t stream) {
    const float* s  = (const float*)d_in[0];
    const void*  mask = d_in[1];
    const float* u  = (const float*)d_in[2];
    const float* W1 = (const float*)d_in[3];
    const float* b1 = (const float*)d_in[4];
    const float* W2 = (const float*)d_in[5];
    const float* b2 = (const float*)d_in[6];
    const float* W3 = (const float*)d_in[7];
    const float* b3 = (const float*)d_in[8];
    const float* Wa = (const float*)d_in[9];
    const float* ba = (const float*)d_in[10];
    const float* Ws = (const float*)d_in[11];
    const float* bs = (const float*)d_in[12];
    float* out = (float*)d_out;
    char* ws = (char*)d_ws;

    // workspace map:
    //   [0,        8,388,608)  A0p packed f16 (K=16384)   (reused by X2p)
    //   [8388608, 13,107,200)  X1p packed f16 (K=9216)
    //   [13107200, ...)        P  f16 [S][256][9216]  (4.72 MB/plane)
    char*  A0p = ws + 0;
    char*  X1p = ws + 8388608;
    char*  X2p = ws + 0;                   // reuses dead A0p
    f16*   P   = (f16*)(ws + 13107200);

    const size_t pbytes = 4718592ull;      // one f16 splitK plane
    int yshift = (ws_size >= 13107200ull + 8 * pbytes) ? 3 : 2;
    const int S = 1 << yshift;

    cvt_kernel<<<2048, 256, 0, stream>>>(s, A0p);

    const int nblk = 72 << yshift;         // 576 @ S=8; y = bid & (S-1)
    gemm_kernel<<<nblk, 256, 0, stream>>>(A0p, 16384, 16384 / S, yshift, W1, P);
    reduce_kernel<<<1152, 256, 0, stream>>>(P, S, b1, X1p);
    gemm_kernel<<<nblk, 256, 0, stream>>>(X1p, DH, DH / S, yshift, W2, P);
    reduce_kernel<<<1152, 256, 0, stream>>>(P, S, b2, X2p);
    gemm_kernel<<<nblk, 256, 0, stream>>>(X2p, DH, DH / S, yshift, W3, P);

    tail_kernel<<<256, 256, 0, stream>>>(P, S, b3, Wa, ba, Ws, bs, mask, u, out);
}